// Round 5
// baseline (170.514 us; speedup 1.0000x reference)
//
#include <hip/hip_runtime.h>
#include <cstdint>
#include <math.h>

#define NB 4
#define NN 512
#define DH 128
#define NHEADS 8
#define NHID 16
#define ITILE 64
#define SENTINEL -1e30f

// ---- fully-fused GAT layer: in-block proj + self-pack + flash attention ----
// 3 dispatches total for the whole model (one per layer), no grid sync.
// Block (b, hh, it): 512 threads.
//   proj phase: thread t computes gl[t][0..15], gr[t][0..15] for its head from
//     hin (or X@Win on the fly for layer 0), W slices staged in LDS (uniform
//     broadcast reads). 8x redundant across i-tiles -- ~2.1M FMA/block, cheap.
//   attn phase: identical math to the verified split-kernel v2 (absmax 0.0):
//     il = t&31 -> rows (i0+il, i0+il+32); js = t>>5 -> 32-j slice; factored
//     lrelu score; two-pass in-register softmax; swizzled LDS merge.
// gl/gr stored f-major ([q][512] float4 chunks): proj writes are stride-16B
// conflict-free; main-loop j reads stay uniform-broadcast.
// Layer 0 packs adj bitmasks (stores adjb for layers 1-2); layer 1 zeroes the
// atomic output target for layer 2 (stream order guarantees visibility).
__global__ __launch_bounds__(512, 1) void gat_layer(
    const int lay,
    const float* __restrict__ X, const float* __restrict__ hin,
    float* __restrict__ hout,
    const float* __restrict__ Win,
    const float* __restrict__ WlL, const float* __restrict__ WrL,
    const float* __restrict__ a_vec, const float* __restrict__ Wout,
    float* __restrict__ out, uint32_t* __restrict__ adjb,
    const int* __restrict__ adj)
{
    __shared__ __align__(16) float smem[23968];     // 95872 B -> 1 block/CU
    float* s_W   = smem;                 // [128][32] f<16:Wl f>=16:Wr (proj)
    float* s_acc = smem + 4096;          // alias over gl/gr region post-main
    float* s_Win = smem + 20480;         // [2][128] (layer 0 only)
    float* s_dgl = smem + 20736;         // [512]
    float* s_dgr = smem + 21248;         // [512]
    float* s_m   = smem + 21760;         // [16][65]
    float* s_l   = smem + 22800;         // [16][65]
    float* s_M   = smem + 23840;         // [64]
    float* s_inv = smem + 23904;         // [64]
    float4* Sgl  = (float4*)(smem + 4096);    // [4][512] f-major chunks
    float4* Sgr  = (float4*)(smem + 12288);   // [4][512]

    const int blk = blockIdx.x;          // 256 = ((b*8+hh)*8) + it
    const int it  = blk & 7;
    const int bh  = blk >> 3;
    const int b   = bh >> 3;
    const int hh  = bh & 7;
    const int i0  = it * ITILE;
    const int t   = threadIdx.x;
    const int il  = t & 31;
    const int js  = t >> 5;              // [0,16)
    const int r0  = i0 + il;
    const int r1  = r0 + 32;

    // ---- stage W head-slices (16 KB) + Win (layer 0) ----
    {
        const int sk = t >> 2, sq = (t & 3) * 4;
        *(float4*)&s_W[sk * 32 + sq]      = *(const float4*)&WlL[sk * DH + hh * NHID + sq];
        *(float4*)&s_W[sk * 32 + 16 + sq] = *(const float4*)&WrL[sk * DH + hh * NHID + sq];
        if (lay == 0 && t < 64) ((float4*)s_Win)[t] = ((const float4*)Win)[t];
    }

    float a[16];
#pragma unroll
    for (int q = 0; q < 4; ++q) {
        const float4 v = ((const float4*)a_vec)[q];
        a[4*q+0] = v.x; a[4*q+1] = v.y; a[4*q+2] = v.z; a[4*q+3] = v.w;
    }

    // ---- masks: layer 0 packs from adj (and stores for reuse); else load ----
    uint32_t mask0, mask1;
    if (lay == 0) {
        const int4* p0 = (const int4*)(adj + ((size_t)(b * NN + r0)) * NN + js * 32);
        const int4* p1 = (const int4*)(adj + ((size_t)(b * NN + r1)) * NN + js * 32);
        uint32_t m0 = 0, m1 = 0;
#pragma unroll
        for (int c = 0; c < 8; ++c) {
            const int4 v0 = p0[c], v1 = p1[c];
            m0 |= (v0.x != 0 ? 1u : 0u) << (c * 4 + 0);
            m0 |= (v0.y != 0 ? 1u : 0u) << (c * 4 + 1);
            m0 |= (v0.z != 0 ? 1u : 0u) << (c * 4 + 2);
            m0 |= (v0.w != 0 ? 1u : 0u) << (c * 4 + 3);
            m1 |= (v1.x != 0 ? 1u : 0u) << (c * 4 + 0);
            m1 |= (v1.y != 0 ? 1u : 0u) << (c * 4 + 1);
            m1 |= (v1.z != 0 ? 1u : 0u) << (c * 4 + 2);
            m1 |= (v1.w != 0 ? 1u : 0u) << (c * 4 + 3);
        }
        mask0 = m0; mask1 = m1;
        adjb[((size_t)(b * NN + r0)) * 16 + js] = m0;   // 8 hh-blocks write same value: benign
        adjb[((size_t)(b * NN + r1)) * 16 + js] = m1;
    } else {
        mask0 = adjb[((size_t)(b * NN + r0)) * 16 + js];
        mask1 = adjb[((size_t)(b * NN + r1)) * 16 + js];
    }
    __syncthreads();                     // s_W/s_Win staged

    // ---- proj: thread t -> row t; gl/gr head slice into regs ----
    float4 agl[4], agr[4];
#pragma unroll
    for (int q = 0; q < 4; ++q) {
        agl[q].x = 0.f; agl[q].y = 0.f; agl[q].z = 0.f; agl[q].w = 0.f;
        agr[q].x = 0.f; agr[q].y = 0.f; agr[q].z = 0.f; agr[q].w = 0.f;
    }
    {
        const float* hrow = (lay > 0) ? (hin + ((size_t)(b * NN + t)) * DH) : nullptr;
        float x0 = 0.f, x1 = 0.f;
        if (lay == 0) {
            x0 = X[(b * NN + t) * 2 + 0];
            x1 = X[(b * NN + t) * 2 + 1];
        }
#pragma unroll 2
        for (int k = 0; k < DH; k += 4) {
            float4 h4;
            if (lay == 0) {
                const float4 w0 = *(const float4*)&s_Win[k];
                const float4 w1 = *(const float4*)&s_Win[DH + k];
                h4.x = x0 * w0.x + x1 * w1.x;
                h4.y = x0 * w0.y + x1 * w1.y;
                h4.z = x0 * w0.z + x1 * w1.z;
                h4.w = x0 * w0.w + x1 * w1.w;
            } else {
                h4 = *(const float4*)&hrow[k];
            }
            const float* hp = &h4.x;
#pragma unroll
            for (int kk = 0; kk < 4; ++kk) {
                const float hk = hp[kk];
                const float* wrow = &s_W[(k + kk) * 32];   // uniform -> broadcast
#pragma unroll
                for (int q = 0; q < 4; ++q) {
                    const float4 wl = *(const float4*)&wrow[q * 4];
                    const float4 wr = *(const float4*)&wrow[16 + q * 4];
                    agl[q].x = fmaf(hk, wl.x, agl[q].x);
                    agl[q].y = fmaf(hk, wl.y, agl[q].y);
                    agl[q].z = fmaf(hk, wl.z, agl[q].z);
                    agl[q].w = fmaf(hk, wl.w, agl[q].w);
                    agr[q].x = fmaf(hk, wr.x, agr[q].x);
                    agr[q].y = fmaf(hk, wr.y, agr[q].y);
                    agr[q].z = fmaf(hk, wr.z, agr[q].z);
                    agr[q].w = fmaf(hk, wr.w, agr[q].w);
                }
            }
        }
    }
    {   // dgl[t] = a . gl[t], dgr[t] = a . gr[t]  (in-thread, no shuffles)
        float dl = 0.f, dr = 0.f;
#pragma unroll
        for (int q = 0; q < 4; ++q) {
            dl = fmaf(a[4*q+0], agl[q].x, dl); dl = fmaf(a[4*q+1], agl[q].y, dl);
            dl = fmaf(a[4*q+2], agl[q].z, dl); dl = fmaf(a[4*q+3], agl[q].w, dl);
            dr = fmaf(a[4*q+0], agr[q].x, dr); dr = fmaf(a[4*q+1], agr[q].y, dr);
            dr = fmaf(a[4*q+2], agr[q].z, dr); dr = fmaf(a[4*q+3], agr[q].w, dr);
        }
        s_dgl[t] = dl;
        s_dgr[t] = dr;
    }
#pragma unroll
    for (int q = 0; q < 4; ++q) {        // f-major stores: stride-16B, conflict-free
        Sgl[q * 512 + t] = agl[q];
        Sgr[q * 512 + t] = agr[q];
    }
    __syncthreads();                     // planes + dgl/dgr ready

    // ---- gri for own 2 rows (one-time strided LDS read, cost negligible) ----
    float gri0[16], gri1[16];
#pragma unroll
    for (int q = 0; q < 4; ++q) {
        const float4 v0 = Sgr[q * 512 + r0];
        const float4 v1 = Sgr[q * 512 + r1];
        gri0[4*q+0] = v0.x; gri0[4*q+1] = v0.y; gri0[4*q+2] = v0.z; gri0[4*q+3] = v0.w;
        gri1[4*q+0] = v1.x; gri1[4*q+1] = v1.y; gri1[4*q+2] = v1.z; gri1[4*q+3] = v1.w;
    }

    // ---- pass 1: scores for 2 rows x 32 j ----
    const float c0 = 0.6f * s_dgr[r0];
    const float c1 = 0.6f * s_dgr[r1];
    const int jbase = js * 32;
    float sc0[32], sc1[32];
#pragma unroll
    for (int jj = 0; jj < 32; ++jj) {
        const int j = jbase + jj;
        const float dj = s_dgl[j];
        float s0 = 0.f, s1 = 0.f;
#pragma unroll
        for (int q = 0; q < 4; ++q) {
            const float4 g = Sgl[q * 512 + j];   // uniform j -> broadcast
            float v;
            v = g.x + gri0[4*q+0]; s0 = fmaf(a[4*q+0], fabsf(v), s0);
            v = g.y + gri0[4*q+1]; s0 = fmaf(a[4*q+1], fabsf(v), s0);
            v = g.z + gri0[4*q+2]; s0 = fmaf(a[4*q+2], fabsf(v), s0);
            v = g.w + gri0[4*q+3]; s0 = fmaf(a[4*q+3], fabsf(v), s0);
            v = g.x + gri1[4*q+0]; s1 = fmaf(a[4*q+0], fabsf(v), s1);
            v = g.y + gri1[4*q+1]; s1 = fmaf(a[4*q+1], fabsf(v), s1);
            v = g.z + gri1[4*q+2]; s1 = fmaf(a[4*q+2], fabsf(v), s1);
            v = g.w + gri1[4*q+3]; s1 = fmaf(a[4*q+3], fabsf(v), s1);
        }
        const float b0 = fmaf(0.6f, dj, c0);
        const float b1 = fmaf(0.6f, dj, c1);
        sc0[jj] = ((mask0 >> jj) & 1u) ? fmaf(0.4f, s0, b0) : SENTINEL;
        sc1[jj] = ((mask1 >> jj) & 1u) ? fmaf(0.4f, s1, b1) : SENTINEL;
    }

    // ---- in-register softmax (two-pass) ----
    float m0 = sc0[0], m1 = sc1[0];
#pragma unroll
    for (int jj = 1; jj < 32; ++jj) { m0 = fmaxf(m0, sc0[jj]); m1 = fmaxf(m1, sc1[jj]); }
    float l0 = 0.f, l1 = 0.f;
#pragma unroll
    for (int jj = 0; jj < 32; ++jj) {
        sc0[jj] = __expf(sc0[jj] - m0); l0 += sc0[jj];
        sc1[jj] = __expf(sc1[jj] - m1); l1 += sc1[jj];
    }
    s_m[js * 65 + il]      = m0;
    s_m[js * 65 + il + 32] = m1;
    s_l[js * 65 + il]      = l0;
    s_l[js * 65 + il + 32] = l1;

    // ---- pass 2: PV aggregation ----
    float acc0[16], acc1[16];
#pragma unroll
    for (int f = 0; f < 16; ++f) { acc0[f] = 0.f; acc1[f] = 0.f; }
#pragma unroll
    for (int jj = 0; jj < 32; ++jj) {
        const int j = jbase + jj;
        const float p0 = sc0[jj], p1 = sc1[jj];
#pragma unroll
        for (int q = 0; q < 4; ++q) {
            const float4 g = Sgr[q * 512 + j];   // broadcast
            acc0[4*q+0] = fmaf(p0, g.x, acc0[4*q+0]);
            acc0[4*q+1] = fmaf(p0, g.y, acc0[4*q+1]);
            acc0[4*q+2] = fmaf(p0, g.z, acc0[4*q+2]);
            acc0[4*q+3] = fmaf(p0, g.w, acc0[4*q+3]);
            acc1[4*q+0] = fmaf(p1, g.x, acc1[4*q+0]);
            acc1[4*q+1] = fmaf(p1, g.y, acc1[4*q+1]);
            acc1[4*q+2] = fmaf(p1, g.z, acc1[4*q+2]);
            acc1[4*q+3] = fmaf(p1, g.w, acc1[4*q+3]);
        }
    }
    __syncthreads();                     // retires gl/gr reads + s_m/s_l writes

    if (t < 64) {                        // per-row global max + denom over 16 slices
        float M = SENTINEL;
#pragma unroll
        for (int k = 0; k < 16; ++k) M = fmaxf(M, s_m[k * 65 + t]);
        float L = 0.f;
#pragma unroll
        for (int k = 0; k < 16; ++k) L += s_l[k * 65 + t] * __expf(s_m[k * 65 + t] - M);
        s_M[t]   = M;
        s_inv[t] = 1.f / L;
    }
    __syncthreads();

    {   // scaled partials into aliased scratch; chunk-XOR swizzle
        const float k0 = __expf(m0 - s_M[il])      * s_inv[il];
        const float k1 = __expf(m1 - s_M[il + 32]) * s_inv[il + 32];
        const int swz = il & 3;
        float* base_a = s_acc + js * 1024;
#pragma unroll
        for (int q = 0; q < 4; ++q) {
            float4 v0, v1;
            v0.x = acc0[4*q+0] * k0; v0.y = acc0[4*q+1] * k0;
            v0.z = acc0[4*q+2] * k0; v0.w = acc0[4*q+3] * k0;
            v1.x = acc1[4*q+0] * k1; v1.y = acc1[4*q+1] * k1;
            v1.z = acc1[4*q+2] * k1; v1.w = acc1[4*q+3] * k1;
            *(float4*)(base_a + il * 16        + 4 * (q ^ swz)) = v0;
            *(float4*)(base_a + (il + 32) * 16 + 4 * (q ^ swz)) = v1;
        }
    }
    __syncthreads();

    {   // final reduce over 16 slices: thread (i = t>>4, f = t&15), 2 rows each
        const int i  = t >> 4;
        const int f  = t & 15;
        const int e  = f & 3, qf = f >> 2;
#pragma unroll
        for (int r = 0; r < 2; ++r) {
            const int lr = i + r * 32;
            const int w  = lr * 16 + 4 * (qf ^ (lr & 3)) + e;
            float o = 0.f;
#pragma unroll
            for (int k = 0; k < 16; ++k) o += s_acc[k * 1024 + w];
            const int grow = i0 + lr;
            if (Wout) {                  // fused h @ W_out partial per head
                float v = o * Wout[hh * NHID + f];
#pragma unroll
                for (int off = 8; off; off >>= 1) v += __shfl_xor(v, off);
                if (f == 0) atomicAdd(out + b * NN + grow, v);
            } else {
                hout[((size_t)(b * NN + grow)) * DH + hh * NHID + f] = o;
            }
        }
    }

    // layer 1 zeroes the atomic target for layer 2 (stream-ordered)
    if (lay == 1 && blk < 4) out[blk * 512 + t] = 0.f;
}

extern "C" void kernel_launch(void* const* d_in, const int* in_sizes, int n_in,
                              void* d_out, int out_size, void* d_ws, size_t ws_size,
                              hipStream_t stream) {
    const float* X    = (const float*)d_in[0];   // [4,512,2]
    const int*   adj  = (const int*)  d_in[1];   // [4,512,512]
    const float* Win  = (const float*)d_in[2];   // [2,128]
    const float* Wl   = (const float*)d_in[3];   // [3,128,128]
    const float* Wr   = (const float*)d_in[4];   // [3,128,128]
    const float* Aa   = (const float*)d_in[5];   // [3,16]
    const float* Wout = (const float*)d_in[6];   // [128,1]
    float* out = (float*)d_out;                  // [4,512] fp32

    float*    ws   = (float*)d_ws;
    float*    h_a  = ws;                         // 1 MB (layer-0 output)
    float*    h_b  = ws + 262144;                // 1 MB (layer-1 output)
    uint32_t* adjb = (uint32_t*)(ws + 524288);   // 128 KB

    gat_layer<<<256, 512, 0, stream>>>(0, X, nullptr, h_a, Win,
        Wl,              Wr,              Aa,      nullptr, out, adjb, adj);
    gat_layer<<<256, 512, 0, stream>>>(1, nullptr, h_a, h_b, Win,
        Wl + DH * DH,    Wr + DH * DH,    Aa + 16, nullptr, out, adjb, adj);
    gat_layer<<<256, 512, 0, stream>>>(2, nullptr, h_b, nullptr, Win,
        Wl + 2 * DH * DH, Wr + 2 * DH * DH, Aa + 32, Wout,  out, adjb, adj);
}